// Round 7
// baseline (165.282 us; speedup 1.0000x reference)
//
#include <hip/hip_runtime.h>

#define NTYPES 6
#define HID 128
#define E_TILE 32

typedef short short8 __attribute__((ext_vector_type(8)));
typedef float f32x4 __attribute__((ext_vector_type(4)));

static __device__ __forceinline__ ushort f2bf(float f) {
    union { float f; unsigned u; } v; v.f = f;
    unsigned r = v.u + 0x7FFFu + ((v.u >> 16) & 1u);   // RNE
    return (ushort)(r >> 16);
}

// mode2 ws layout: hdr[32] | ncnt[N] | noff[N+1] | bsum[256] | arr[E] | sortedT[6*CAP] | Wt | Sb | msgs

// fused: zero(hdr+ncnt) || state f32->bf16 || W transpose/convert  (block-range split)
__global__ void k_prep(int4* __restrict__ zp, int n4,
                       const float* __restrict__ Sf, ushort* __restrict__ Sb, int total,
                       const float* __restrict__ W, ushort* __restrict__ Wt,
                       int zb, int sb) {
    int b = blockIdx.x;
    if (b < zb) {
        int i = b * 256 + threadIdx.x;
        if (i < n4) zp[i] = make_int4(0, 0, 0, 0);
    } else if (b < zb + sb) {
        int g = ((b - zb) * 256 + threadIdx.x) * 8;
        if (g < total) {
            float4 a = *(const float4*)(Sf + g);
            float4 c = *(const float4*)(Sf + g + 4);
            ushort t[8] = { f2bf(a.x), f2bf(a.y), f2bf(a.z), f2bf(a.w),
                            f2bf(c.x), f2bf(c.y), f2bf(c.z), f2bf(c.w) };
            *(short8*)(Sb + g) = *(short8*)t;
        }
    } else {
        int t = (b - zb - sb) * 256 + threadIdx.x;
        int n  = t & 127;
        int k8 = (t >> 7) & 31;
        int ty = t >> 12;
        if (ty >= NTYPES) return;
        const float* wp = W + ((size_t)ty * 256 + (size_t)k8 * 8) * HID + n;
        ushort tmp[8];
        #pragma unroll
        for (int j = 0; j < 8; ++j) tmp[j] = f2bf(wp[(size_t)j * HID]);
        *(short8*)(Wt + ((size_t)ty * HID + n) * 256 + k8 * 8) = *(short8*)tmp;
    }
}

// single-pass binning: LDS type hist + append into fixed regions t*CAP, plus tgt arrival rank
template <int RANK>
__global__ void k_bin(const int* __restrict__ etype, const int* __restrict__ tgt, int E, int CAP,
                      int* __restrict__ hdr, int* __restrict__ ncnt,
                      int* __restrict__ arr, int* __restrict__ sortedT) {
    __shared__ int lcnt[NTYPES];
    __shared__ int lbase[NTYPES];
    if (threadIdx.x < NTYPES) lcnt[threadIdx.x] = 0;
    __syncthreads();
    int i = blockIdx.x * 256 + threadIdx.x;
    int t = 0, lr = 0;
    bool valid = (i < E);
    if (valid) {
        t = etype[i] - 1;
        lr = atomicAdd(&lcnt[t], 1);
        if (RANK) arr[i] = atomicAdd(&ncnt[tgt[i]], 1);
    }
    __syncthreads();
    if (threadIdx.x < NTYPES) {
        int c = lcnt[threadIdx.x];
        lbase[threadIdx.x] = c ? atomicAdd(&hdr[16 + threadIdx.x], c) : 0;
    }
    __syncthreads();
    if (valid) {
        int pos = lbase[t] + lr;
        if (pos < CAP) sortedT[t * CAP + pos] = i;
    }
}

// per-1024-chunk exclusive scan; bsum[b] = chunk total
__global__ void k_scan1(const int* __restrict__ ncnt, int* __restrict__ noff,
                        int* __restrict__ bsum, int N) {
    __shared__ int s[256];
    const int b = blockIdx.x, t = threadIdx.x;
    const int base = b * 1024 + t * 4;
    int v[4];
    #pragma unroll
    for (int i = 0; i < 4; ++i) v[i] = (base + i < N) ? ncnt[base + i] : 0;
    int tsum = v[0] + v[1] + v[2] + v[3];
    s[t] = tsum;
    __syncthreads();
    for (int off = 1; off < 256; off <<= 1) {
        int x = (t >= off) ? s[t - off] : 0;
        __syncthreads();
        s[t] += x;
        __syncthreads();
    }
    if (t == 255) bsum[b] = s[255];
    int run = s[t] - tsum;
    #pragma unroll
    for (int i = 0; i < 4; ++i)
        if (base + i < N) { noff[base + i] = run; run += v[i]; }
}

__global__ void k_scan2(int* __restrict__ bsum, int nb) {
    __shared__ int s[256];
    const int t = threadIdx.x;
    int v = (t < nb) ? bsum[t] : 0;
    s[t] = v;
    __syncthreads();
    for (int off = 1; off < 256; off <<= 1) {
        int x = (t >= off) ? s[t - off] : 0;
        __syncthreads();
        s[t] += x;
        __syncthreads();
    }
    if (t < nb) bsum[t] = s[t] - v;   // exclusive
}

// W-only conversion (fallback path)
__global__ void k_wconv(const float* __restrict__ W, ushort* __restrict__ Wt) {
    int t = blockIdx.x * blockDim.x + threadIdx.x;
    int n  = t & 127;
    int k8 = (t >> 7) & 31;
    int ty = t >> 12;
    if (ty >= NTYPES) return;
    const float* wp = W + ((size_t)ty * 256 + (size_t)k8 * 8) * HID + n;
    ushort tmp[8];
    #pragma unroll
    for (int j = 0; j < 8; ++j) tmp[j] = f2bf(wp[(size_t)j * HID]);
    *(short8*)(Wt + ((size_t)ty * HID + n) * 256 + k8 * 8) = *(short8*)tmp;
}

__global__ void k_zero32(int* __restrict__ p) {
    if (threadIdx.x < 32) p[threadIdx.x] = 0;
}

// ---------------- GEMM ----------------
// One block = 32 edges of one type x 128 cols, K=256, bf16 MFMA.
// MODE 2: bf16 gather -> msgs write. MODE 0: f32 gather -> atomic scatter.
template <int MODE>
__launch_bounds__(256, 6)
__global__ void k_gemm(const ushort* __restrict__ Sb, const float* __restrict__ Sf,
                       const int* __restrict__ src, const int* __restrict__ tgt,
                       const ushort* __restrict__ Wt, const int* __restrict__ hdr,
                       const int* __restrict__ sortedT, int CAP,
                       const int* __restrict__ noff, const int* __restrict__ bsum,
                       const int* __restrict__ arr,
                       ushort* __restrict__ msgs, float* __restrict__ out) {
    __shared__ __align__(16) ushort Xs[E_TILE][264];   // 16896 B
    __shared__ int sN[E_TILE];
    __shared__ int tN[E_TILE];
    __shared__ int dstR[E_TILE];

    // map blockIdx -> (type, tile) from final cursor counts
    int tile = blockIdx.x;
    int ty, base = 0, cnt = 0;
    for (ty = 0; ty < NTYPES; ++ty) {
        int c = hdr[16 + ty];
        if (c > CAP) c = CAP;
        int nt = (c + E_TILE - 1) / E_TILE;
        if (tile < nt) {
            base = ty * CAP + tile * E_TILE;
            cnt = c - tile * E_TILE;
            if (cnt > E_TILE) cnt = E_TILE;
            break;
        }
        tile -= nt;
    }
    if (ty == NTYPES) return;

    const int tid = threadIdx.x;
    if (tid < E_TILE) {
        int sn = 0, tn = 0, dr = 0;
        if (tid < cnt) {
            int e = sortedT[base + tid];
            sn = src[e]; tn = tgt[e];
            if (MODE == 2) dr = noff[tn] + bsum[tn >> 10] + arr[e];
        }
        sN[tid] = sn; tN[tid] = tn; dstR[tid] = dr;
    }
    __syncthreads();

    // ---- stage X = [state[src] | state[tgt]] bf16 [32][256]; 8 threads/edge ----
    {
        const int e = tid >> 3, q = tid & 7;     // thread covers 32 ushorts (64 B)
        ushort* dp = &Xs[e][q * 32];
        if (e < cnt) {
            const int node = (q & 4) ? tN[e] : sN[e];
            if (MODE == 2) {
                const ushort* rp = Sb + (size_t)node * HID + (q & 3) * 32;
                short8 v0 = *(const short8*)(rp);
                short8 v1 = *(const short8*)(rp + 8);
                short8 v2 = *(const short8*)(rp + 16);
                short8 v3 = *(const short8*)(rp + 24);
                *(short8*)(dp)      = v0;
                *(short8*)(dp + 8)  = v1;
                *(short8*)(dp + 16) = v2;
                *(short8*)(dp + 24) = v3;
            } else {
                const float* rp = Sf + (size_t)node * HID + (q & 3) * 32;
                #pragma unroll
                for (int i = 0; i < 4; ++i) {
                    float4 a = *(const float4*)(rp + i * 8);
                    float4 b = *(const float4*)(rp + i * 8 + 4);
                    ushort tmp[8] = { f2bf(a.x), f2bf(a.y), f2bf(a.z), f2bf(a.w),
                                      f2bf(b.x), f2bf(b.y), f2bf(b.z), f2bf(b.w) };
                    *(short8*)(dp + i * 8) = *(short8*)tmp;
                }
            }
        } else {
            short8 z = (short8){0, 0, 0, 0, 0, 0, 0, 0};
            #pragma unroll
            for (int i = 0; i < 4; ++i) *(short8*)(dp + i * 8) = z;
        }
    }
    __syncthreads();

    // ---- MFMA: wave w -> 32 edges x cols [w*32, w*32+32) ----
    const int w  = tid >> 6;
    const int l  = tid & 63;
    const int lr = l & 15;
    const int lg = l >> 4;

    f32x4 acc[2][2];
    #pragma unroll
    for (int mf = 0; mf < 2; ++mf)
        #pragma unroll
        for (int nf = 0; nf < 2; ++nf)
            acc[mf][nf] = (f32x4){0.f, 0.f, 0.f, 0.f};

    const ushort* wb = Wt + ((size_t)ty * HID + w * 32 + lr) * 256 + 8 * lg;  // L2-hot
    const ushort* xb = &Xs[lr][8 * lg];

    #pragma unroll
    for (int kk = 0; kk < 8; ++kk) {
        const int k0 = kk * 32;
        short8 b0 = *(const short8*)(wb + k0);
        short8 b1 = *(const short8*)(wb + 16 * 256 + k0);
        short8 a0 = *(const short8*)(xb + k0);
        short8 a1 = *(const short8*)(xb + 16 * 264 + k0);
        acc[0][0] = __builtin_amdgcn_mfma_f32_16x16x32_bf16(a0, b0, acc[0][0], 0, 0, 0);
        acc[0][1] = __builtin_amdgcn_mfma_f32_16x16x32_bf16(a0, b1, acc[0][1], 0, 0, 0);
        acc[1][0] = __builtin_amdgcn_mfma_f32_16x16x32_bf16(a1, b0, acc[1][0], 0, 0, 0);
        acc[1][1] = __builtin_amdgcn_mfma_f32_16x16x32_bf16(a1, b1, acc[1][1], 0, 0, 0);
    }

    // ---- epilogue ----
    __syncthreads();
    float (*Os)[132] = (float (*)[132])&Xs[0][0];   // 32*132*4 = 16896 B exactly
    #pragma unroll
    for (int mf = 0; mf < 2; ++mf)
        #pragma unroll
        for (int nf = 0; nf < 2; ++nf)
            #pragma unroll
            for (int r = 0; r < 4; ++r)
                Os[mf * 16 + lg * 4 + r][w * 32 + nf * 16 + lr] = acc[mf][nf][r];
    __syncthreads();

    if (MODE == 2) {
        const int row0 = tid >> 4, cg = tid & 15;
        #pragma unroll
        for (int rr = 0; rr < 2; ++rr) {
            int row = rr * 16 + row0;
            if (row < cnt) {
                float4 a = *(const float4*)&Os[row][cg * 8];
                float4 b = *(const float4*)&Os[row][cg * 8 + 4];
                ushort tmp[8] = { f2bf(a.x), f2bf(a.y), f2bf(a.z), f2bf(a.w),
                                  f2bf(b.x), f2bf(b.y), f2bf(b.z), f2bf(b.w) };
                *(short8*)(msgs + (size_t)dstR[row] * HID + cg * 8) = *(short8*)tmp;
            }
        }
    } else {
        const int rA = tid >> 7;
        const int c  = tid & (HID - 1);
        for (int it = 0; it < E_TILE / 2; ++it) {
            int ee = it * 2 + rA;
            if (ee < cnt) atomicAdd(&out[(size_t)tN[ee] * HID + c], Os[ee][c]);
        }
    }
}

// each 64-lane group owns one node: sum its msgs rows, write out once
__launch_bounds__(256)
__global__ void k_scatter(const ushort* __restrict__ msgs, const int* __restrict__ noff,
                          const int* __restrict__ bsum, float* __restrict__ out,
                          int N, int Etot) {
    int node = blockIdx.x * 4 + (threadIdx.x >> 6);
    if (node >= N) return;
    int cp = threadIdx.x & 63;
    int s = noff[node] + bsum[node >> 10];
    int e = (node + 1 < N) ? (noff[node + 1] + bsum[(node + 1) >> 10]) : Etot;
    float a0 = 0.f, a1 = 0.f;
    for (int r = s; r < e; ++r) {
        unsigned u = *(const unsigned*)(msgs + (size_t)r * HID + cp * 2);
        union { unsigned u; float f; } lo, hi;
        lo.u = u << 16; hi.u = u & 0xFFFF0000u;
        a0 += lo.f; a1 += hi.f;
    }
    *(float2*)(out + (size_t)node * HID + cp * 2) = make_float2(a0, a1);
}

extern "C" void kernel_launch(void* const* d_in, const int* in_sizes, int n_in,
                              void* d_out, int out_size, void* d_ws, size_t ws_size,
                              hipStream_t stream) {
    const float* Sf    = (const float*)d_in[0];
    const int*   edges = (const int*)d_in[1];
    const float* W     = (const float*)d_in[2];
    float* out = (float*)d_out;

    const int E = in_sizes[1] / 3;
    const int N = in_sizes[0] / HID;
    const int* etype = edges;
    const int* src   = edges + E;
    const int* tgt   = edges + 2 * E;
    int* ws = (int*)d_ws;

    const int CAP = E / 5 + 4096;   // per-type region capacity (>100 sigma margin)

    // mode2 layout
    int* ncnt    = ws + 32;
    int* noff    = ncnt + N;
    int* bsum    = noff + N + 1;
    int* arr     = bsum + 256;
    int* sortedT = arr + E;
    size_t intsEnd = (size_t)(32 + N + (N + 1) + 256 + (size_t)E + 6 * (size_t)CAP) * sizeof(int);
    size_t wtOff   = (intsEnd + 255) & ~(size_t)255;
    size_t sbOff   = ((wtOff + (size_t)NTYPES * HID * 256 * 2) + 255) & ~(size_t)255;
    size_t msgsOff = ((sbOff + (size_t)N * HID * 2) + 255) & ~(size_t)255;
    size_t need2   = msgsOff + (size_t)E * HID * 2;

    const int nb1 = (N + 1023) / 1024;
    const int nblocks = (E + E_TILE - 1) / E_TILE + NTYPES;
    const int eb = (E + 255) / 256;
    ushort* Wt = (ushort*)((char*)d_ws + wtOff);

    if (ws_size >= need2 && nb1 <= 256) {
        ushort* Sb   = (ushort*)((char*)d_ws + sbOff);
        ushort* msgs = (ushort*)((char*)d_ws + msgsOff);
        const int total = N * HID;
        const int n4 = (32 + N + 3) / 4;
        const int zb = (n4 + 255) / 256;
        const int sb = (total / 8 + 255) / 256;
        const int wb = (NTYPES * HID * 32 + 255) / 256;

        k_prep<<<zb + sb + wb, 256, 0, stream>>>((int4*)ws, n4, Sf, Sb, total, W, Wt, zb, sb);
        k_bin<1><<<eb, 256, 0, stream>>>(etype, tgt, E, CAP, ws, ncnt, arr, sortedT);
        k_scan1<<<nb1, 256, 0, stream>>>(ncnt, noff, bsum, N);
        k_scan2<<<1, 256, 0, stream>>>(bsum, nb1);
        k_gemm<2><<<nblocks, 256, 0, stream>>>(Sb, Sf, src, tgt, Wt, ws, sortedT, CAP,
                                               noff, bsum, arr, msgs, out);
        k_scatter<<<(N + 3) / 4, 256, 0, stream>>>(msgs, noff, bsum, out, N, E);
    } else {
        // fallback: type-bin + atomic scatter (small ws): hdr[32] | sortedT[6*CAP] | Wt
        int* sortedT0 = ws + 32;
        size_t wt0Off = (((size_t)(32 + 6 * (size_t)CAP) * sizeof(int)) + 255) & ~(size_t)255;
        ushort* Wt0 = (ushort*)((char*)d_ws + wt0Off);

        k_zero32<<<1, 64, 0, stream>>>(ws);
        hipMemsetAsync(d_out, 0, (size_t)out_size * sizeof(float), stream);
        k_bin<0><<<eb, 256, 0, stream>>>(etype, tgt, E, CAP, ws, nullptr, nullptr, sortedT0);
        k_wconv<<<(NTYPES * HID * 32) / 256, 256, 0, stream>>>(W, Wt0);
        k_gemm<0><<<nblocks, 256, 0, stream>>>(nullptr, Sf, src, tgt, Wt0, ws, sortedT0, CAP,
                                               nullptr, nullptr, nullptr, nullptr, out);
    }
}

// Round 8
// 137.984 us; speedup vs baseline: 1.1978x; 1.1978x over previous
//
#include <hip/hip_runtime.h>

#define NTYPES 6
#define HID 128
#define E_TILE 64
#define TPB 4

typedef short short8 __attribute__((ext_vector_type(8)));
typedef float f32x4 __attribute__((ext_vector_type(4)));

static __device__ __forceinline__ ushort f2bf(float f) {
    union { float f; unsigned u; } v; v.f = f;
    unsigned r = v.u + 0x7FFFu + ((v.u >> 16) & 1u);   // RNE
    return (ushort)(r >> 16);
}

// mode2 ws layout: hdr[32] | ncnt[N] | noff[N+1] | bsum[256] | arr[E] | sortedT[6*CAP] | Wt | Sb | msgs

// fused: zero(hdr+ncnt) || state f32->bf16 || W transpose/convert  (block-range split)
__global__ void k_prep(int4* __restrict__ zp, int n4,
                       const float* __restrict__ Sf, ushort* __restrict__ Sb, int total,
                       const float* __restrict__ W, ushort* __restrict__ Wt,
                       int zb, int sb) {
    int b = blockIdx.x;
    if (b < zb) {
        int i = b * 256 + threadIdx.x;
        if (i < n4) zp[i] = make_int4(0, 0, 0, 0);
    } else if (b < zb + sb) {
        int g = ((b - zb) * 256 + threadIdx.x) * 8;
        if (g < total) {
            float4 a = *(const float4*)(Sf + g);
            float4 c = *(const float4*)(Sf + g + 4);
            ushort t[8] = { f2bf(a.x), f2bf(a.y), f2bf(a.z), f2bf(a.w),
                            f2bf(c.x), f2bf(c.y), f2bf(c.z), f2bf(c.w) };
            *(short8*)(Sb + g) = *(short8*)t;
        }
    } else {
        int t = (b - zb - sb) * 256 + threadIdx.x;
        int n  = t & 127;
        int k8 = (t >> 7) & 31;
        int ty = t >> 12;
        if (ty >= NTYPES) return;
        const float* wp = W + ((size_t)ty * 256 + (size_t)k8 * 8) * HID + n;
        ushort tmp[8];
        #pragma unroll
        for (int j = 0; j < 8; ++j) tmp[j] = f2bf(wp[(size_t)j * HID]);
        *(short8*)(Wt + ((size_t)ty * HID + n) * 256 + k8 * 8) = *(short8*)tmp;
    }
}

// single-pass binning: LDS type hist + append into fixed regions t*CAP, plus tgt arrival rank
template <int RANK>
__global__ void k_bin(const int* __restrict__ etype, const int* __restrict__ tgt, int E, int CAP,
                      int* __restrict__ hdr, int* __restrict__ ncnt,
                      int* __restrict__ arr, int* __restrict__ sortedT) {
    __shared__ int lcnt[NTYPES];
    __shared__ int lbase[NTYPES];
    if (threadIdx.x < NTYPES) lcnt[threadIdx.x] = 0;
    __syncthreads();
    int i = blockIdx.x * 256 + threadIdx.x;
    int t = 0, lr = 0;
    bool valid = (i < E);
    if (valid) {
        t = etype[i] - 1;
        lr = atomicAdd(&lcnt[t], 1);
        if (RANK) arr[i] = atomicAdd(&ncnt[tgt[i]], 1);
    }
    __syncthreads();
    if (threadIdx.x < NTYPES) {
        int c = lcnt[threadIdx.x];
        lbase[threadIdx.x] = c ? atomicAdd(&hdr[16 + threadIdx.x], c) : 0;
    }
    __syncthreads();
    if (valid) {
        int pos = lbase[t] + lr;
        if (pos < CAP) sortedT[t * CAP + pos] = i;
    }
}

// per-1024-chunk exclusive scan; bsum[b] = chunk total
__global__ void k_scan1(const int* __restrict__ ncnt, int* __restrict__ noff,
                        int* __restrict__ bsum, int N) {
    __shared__ int s[256];
    const int b = blockIdx.x, t = threadIdx.x;
    const int base = b * 1024 + t * 4;
    int v[4];
    #pragma unroll
    for (int i = 0; i < 4; ++i) v[i] = (base + i < N) ? ncnt[base + i] : 0;
    int tsum = v[0] + v[1] + v[2] + v[3];
    s[t] = tsum;
    __syncthreads();
    for (int off = 1; off < 256; off <<= 1) {
        int x = (t >= off) ? s[t - off] : 0;
        __syncthreads();
        s[t] += x;
        __syncthreads();
    }
    if (t == 255) bsum[b] = s[255];
    int run = s[t] - tsum;
    #pragma unroll
    for (int i = 0; i < 4; ++i)
        if (base + i < N) { noff[base + i] = run; run += v[i]; }
}

__global__ void k_scan2(int* __restrict__ bsum, int nb) {
    __shared__ int s[256];
    const int t = threadIdx.x;
    int v = (t < nb) ? bsum[t] : 0;
    s[t] = v;
    __syncthreads();
    for (int off = 1; off < 256; off <<= 1) {
        int x = (t >= off) ? s[t - off] : 0;
        __syncthreads();
        s[t] += x;
        __syncthreads();
    }
    if (t < nb) bsum[t] = s[t] - v;   // exclusive
}

// W-only conversion (fallback path)
__global__ void k_wconv(const float* __restrict__ W, ushort* __restrict__ Wt) {
    int t = blockIdx.x * blockDim.x + threadIdx.x;
    int n  = t & 127;
    int k8 = (t >> 7) & 31;
    int ty = t >> 12;
    if (ty >= NTYPES) return;
    const float* wp = W + ((size_t)ty * 256 + (size_t)k8 * 8) * HID + n;
    ushort tmp[8];
    #pragma unroll
    for (int j = 0; j < 8; ++j) tmp[j] = f2bf(wp[(size_t)j * HID]);
    *(short8*)(Wt + ((size_t)ty * HID + n) * 256 + k8 * 8) = *(short8*)tmp;
}

__global__ void k_zero32(int* __restrict__ p) {
    if (threadIdx.x < 32) p[threadIdx.x] = 0;
}

// ---------------- GEMM ----------------
// One block = TPB consecutive 64-edge tiles of ONE type x 128 cols, K=256, bf16 MFMA.
// W fragments live in registers for the whole block (amortized across TPB tiles).
// MODE 2: bf16 gather -> msgs write. MODE 0: f32 gather -> atomic scatter.
template <int MODE>
__launch_bounds__(256, 4)
__global__ void k_gemm(const ushort* __restrict__ Sb, const float* __restrict__ Sf,
                       const int* __restrict__ src, const int* __restrict__ tgt,
                       const ushort* __restrict__ Wt, const int* __restrict__ hdr,
                       const int* __restrict__ sortedT, int CAP,
                       const int* __restrict__ noff, const int* __restrict__ bsum,
                       const int* __restrict__ arr,
                       ushort* __restrict__ msgs, float* __restrict__ out) {
    __shared__ __align__(16) ushort Xs[E_TILE][264];   // 33792 B
    __shared__ int sN[TPB][E_TILE];
    __shared__ int tN[TPB][E_TILE];
    __shared__ int dstR[TPB][E_TILE];

    // map blockIdx -> (type, tile-group) from final cursor counts
    int g = blockIdx.x;
    int ty, t0 = 0, ntl = 0, cnt_t = 0;
    for (ty = 0; ty < NTYPES; ++ty) {
        int c = hdr[16 + ty];
        if (c > CAP) c = CAP;
        int nt = (c + E_TILE - 1) >> 6;
        int ng = (nt + TPB - 1) / TPB;
        if (g < ng) {
            t0 = g * TPB;
            ntl = nt - t0; if (ntl > TPB) ntl = TPB;
            cnt_t = c;
            break;
        }
        g -= ng;
    }
    if (ty == NTYPES) return;

    const int tid = threadIdx.x;
    const int w  = tid >> 6;
    const int l  = tid & 63;
    const int lr = l & 15;
    const int lg = l >> 4;

    // prefetch indices for ALL tiles of this block: tile = tid>>6, slot = tid&63
    {
        const int tt = tid >> 6, s = l;
        if (tt < ntl) {
            int gidx = (t0 + tt) * E_TILE + s;
            int sn = 0, tn = 0, dr = 0;
            if (gidx < cnt_t) {
                int e = sortedT[ty * CAP + gidx];
                sn = src[e]; tn = tgt[e];
                if (MODE == 2) dr = noff[tn] + bsum[tn >> 10] + arr[e];
            }
            sN[tt][s] = sn; tN[tt][s] = tn; dstR[tt][s] = dr;
        }
    }

    // prefetch all W fragments for this wave into registers (held across tiles)
    short8 wreg[16];
    {
        const ushort* wb = Wt + ((size_t)ty * HID + w * 32 + lr) * 256 + 8 * lg;
        #pragma unroll
        for (int kk = 0; kk < 8; ++kk) {
            wreg[2 * kk]     = *(const short8*)(wb + kk * 32);
            wreg[2 * kk + 1] = *(const short8*)(wb + 16 * 256 + kk * 32);
        }
    }
    __syncthreads();

    for (int tt = 0; tt < ntl; ++tt) {
        int cnt = cnt_t - (t0 + tt) * E_TILE;
        if (cnt > E_TILE) cnt = E_TILE;

        // ---- stage X = [state[src] | state[tgt]] bf16 [64][256]; 4 threads/edge ----
        {
            const int e = tid >> 2, q = tid & 3;   // thread covers 64 ushorts (128 B)
            ushort* dp = &Xs[e][q * 64];
            if (e < cnt) {
                const int node = (q & 2) ? tN[tt][e] : sN[tt][e];
                if (MODE == 2) {
                    const ushort* rp = Sb + (size_t)node * HID + (q & 1) * 64;
                    short8 v[8];
                    #pragma unroll
                    for (int i = 0; i < 8; ++i) v[i] = *(const short8*)(rp + i * 8);
                    #pragma unroll
                    for (int i = 0; i < 8; ++i) *(short8*)(dp + i * 8) = v[i];
                } else {
                    const float* rp = Sf + (size_t)node * HID + (q & 1) * 64;
                    #pragma unroll
                    for (int i = 0; i < 8; ++i) {
                        float4 a = *(const float4*)(rp + i * 8);
                        float4 b = *(const float4*)(rp + i * 8 + 4);
                        ushort tmp[8] = { f2bf(a.x), f2bf(a.y), f2bf(a.z), f2bf(a.w),
                                          f2bf(b.x), f2bf(b.y), f2bf(b.z), f2bf(b.w) };
                        *(short8*)(dp + i * 8) = *(short8*)tmp;
                    }
                }
            } else {
                short8 z = (short8){0, 0, 0, 0, 0, 0, 0, 0};
                #pragma unroll
                for (int i = 0; i < 8; ++i) *(short8*)(dp + i * 8) = z;
            }
        }
        __syncthreads();

        // ---- MFMA: wave w -> 64 edges x cols [w*32, w*32+32) ----
        f32x4 acc[4][2];
        #pragma unroll
        for (int mf = 0; mf < 4; ++mf)
            #pragma unroll
            for (int nf = 0; nf < 2; ++nf)
                acc[mf][nf] = (f32x4){0.f, 0.f, 0.f, 0.f};

        const ushort* xb = &Xs[lr][8 * lg];
        #pragma unroll
        for (int kk = 0; kk < 8; ++kk) {
            const int k0 = kk * 32;
            #pragma unroll
            for (int mf = 0; mf < 4; ++mf) {
                short8 a = *(const short8*)(xb + mf * 16 * 264 + k0);
                acc[mf][0] = __builtin_amdgcn_mfma_f32_16x16x32_bf16(a, wreg[2 * kk],     acc[mf][0], 0, 0, 0);
                acc[mf][1] = __builtin_amdgcn_mfma_f32_16x16x32_bf16(a, wreg[2 * kk + 1], acc[mf][1], 0, 0, 0);
            }
        }
        __syncthreads();   // all Xs reads done before Os overlay

        // ---- epilogue: acc -> Os (overlay on Xs) ----
        float (*Os)[132] = (float (*)[132])&Xs[0][0];   // 64*132*4 = 33792 B exactly
        #pragma unroll
        for (int mf = 0; mf < 4; ++mf)
            #pragma unroll
            for (int nf = 0; nf < 2; ++nf)
                #pragma unroll
                for (int r = 0; r < 4; ++r)
                    Os[mf * 16 + lg * 4 + r][w * 32 + nf * 16 + lr] = acc[mf][nf][r];
        __syncthreads();

        if (MODE == 2) {
            const int r8 = tid >> 4, cg = tid & 15;
            #pragma unroll
            for (int rr = 0; rr < 4; ++rr) {
                int row = rr * 16 + r8;
                if (row < cnt) {
                    float4 a = *(const float4*)&Os[row][cg * 8];
                    float4 b = *(const float4*)&Os[row][cg * 8 + 4];
                    ushort tmp[8] = { f2bf(a.x), f2bf(a.y), f2bf(a.z), f2bf(a.w),
                                      f2bf(b.x), f2bf(b.y), f2bf(b.z), f2bf(b.w) };
                    *(short8*)(msgs + (size_t)dstR[tt][row] * HID + cg * 8) = *(short8*)tmp;
                }
            }
        } else {
            const int rA = tid >> 7;
            const int c  = tid & (HID - 1);
            for (int it = 0; it < E_TILE / 2; ++it) {
                int ee = it * 2 + rA;
                if (ee < cnt) atomicAdd(&out[(size_t)tN[tt][ee] * HID + c], Os[ee][c]);
            }
        }
        __syncthreads();   // Os reads done before next tile's staging overwrites Xs
    }
}

// each 64-lane group owns one node: sum its msgs rows, write out once
__launch_bounds__(256)
__global__ void k_scatter(const ushort* __restrict__ msgs, const int* __restrict__ noff,
                          const int* __restrict__ bsum, float* __restrict__ out,
                          int N, int Etot) {
    int node = blockIdx.x * 4 + (threadIdx.x >> 6);
    if (node >= N) return;
    int cp = threadIdx.x & 63;
    int s = noff[node] + bsum[node >> 10];
    int e = (node + 1 < N) ? (noff[node + 1] + bsum[(node + 1) >> 10]) : Etot;
    float a0 = 0.f, a1 = 0.f;
    for (int r = s; r < e; ++r) {
        unsigned u = *(const unsigned*)(msgs + (size_t)r * HID + cp * 2);
        union { unsigned u; float f; } lo, hi;
        lo.u = u << 16; hi.u = u & 0xFFFF0000u;
        a0 += lo.f; a1 += hi.f;
    }
    *(float2*)(out + (size_t)node * HID + cp * 2) = make_float2(a0, a1);
}

extern "C" void kernel_launch(void* const* d_in, const int* in_sizes, int n_in,
                              void* d_out, int out_size, void* d_ws, size_t ws_size,
                              hipStream_t stream) {
    const float* Sf    = (const float*)d_in[0];
    const int*   edges = (const int*)d_in[1];
    const float* W     = (const float*)d_in[2];
    float* out = (float*)d_out;

    const int E = in_sizes[1] / 3;
    const int N = in_sizes[0] / HID;
    const int* etype = edges;
    const int* src   = edges + E;
    const int* tgt   = edges + 2 * E;
    int* ws = (int*)d_ws;

    const int CAP = E / 5 + 4096;   // per-type region capacity (>100 sigma margin)

    // mode2 layout
    int* ncnt    = ws + 32;
    int* noff    = ncnt + N;
    int* bsum    = noff + N + 1;
    int* arr     = bsum + 256;
    int* sortedT = arr + E;
    size_t intsEnd = (size_t)(32 + N + (N + 1) + 256 + (size_t)E + 6 * (size_t)CAP) * sizeof(int);
    size_t wtOff   = (intsEnd + 255) & ~(size_t)255;
    size_t sbOff   = ((wtOff + (size_t)NTYPES * HID * 256 * 2) + 255) & ~(size_t)255;
    size_t msgsOff = ((sbOff + (size_t)N * HID * 2) + 255) & ~(size_t)255;
    size_t need2   = msgsOff + (size_t)E * HID * 2;

    const int nb1 = (N + 1023) / 1024;
    // per-type rounding can add up to 1 group per type -> + 2*NTYPES slack
    const int nblocks = (E + E_TILE * TPB - 1) / (E_TILE * TPB) + 2 * NTYPES;
    const int eb = (E + 255) / 256;
    ushort* Wt = (ushort*)((char*)d_ws + wtOff);

    if (ws_size >= need2 && nb1 <= 256) {
        ushort* Sb   = (ushort*)((char*)d_ws + sbOff);
        ushort* msgs = (ushort*)((char*)d_ws + msgsOff);
        const int total = N * HID;
        const int n4 = (32 + N + 3) / 4;
        const int zb = (n4 + 255) / 256;
        const int sb = (total / 8 + 255) / 256;
        const int wb = (NTYPES * HID * 32 + 255) / 256;

        k_prep<<<zb + sb + wb, 256, 0, stream>>>((int4*)ws, n4, Sf, Sb, total, W, Wt, zb, sb);
        k_bin<1><<<eb, 256, 0, stream>>>(etype, tgt, E, CAP, ws, ncnt, arr, sortedT);
        k_scan1<<<nb1, 256, 0, stream>>>(ncnt, noff, bsum, N);
        k_scan2<<<1, 256, 0, stream>>>(bsum, nb1);
        k_gemm<2><<<nblocks, 256, 0, stream>>>(Sb, Sf, src, tgt, Wt, ws, sortedT, CAP,
                                               noff, bsum, arr, msgs, out);
        k_scatter<<<(N + 3) / 4, 256, 0, stream>>>(msgs, noff, bsum, out, N, E);
    } else {
        // fallback: type-bin + atomic scatter (small ws): hdr[32] | sortedT[6*CAP] | Wt
        int* sortedT0 = ws + 32;
        size_t wt0Off = (((size_t)(32 + 6 * (size_t)CAP) * sizeof(int)) + 255) & ~(size_t)255;
        ushort* Wt0 = (ushort*)((char*)d_ws + wt0Off);

        k_zero32<<<1, 64, 0, stream>>>(ws);
        hipMemsetAsync(d_out, 0, (size_t)out_size * sizeof(float), stream);
        k_bin<0><<<eb, 256, 0, stream>>>(etype, tgt, E, CAP, ws, nullptr, nullptr, sortedT0);
        k_wconv<<<(NTYPES * HID * 32) / 256, 256, 0, stream>>>(W, Wt0);
        k_gemm<0><<<nblocks, 256, 0, stream>>>(nullptr, Sf, src, tgt, Wt0, ws, sortedT0, CAP,
                                               nullptr, nullptr, nullptr, nullptr, out);
    }
}